// Round 8
// baseline (398.306 us; speedup 1.0000x reference)
//
#include <hip/hip_runtime.h>
#include <stdint.h>

// Problem constants
#define BB 32
#define FO 520          // F*O
#define M1 16640        // BB*FO
#define KIN 2048        // IN
#define KA 2112         // IN + 64 (S-matrix columns folded into K)
#define N1 1024         // 2*G (concatenated rel|tem)
#define GG 512          // G
#define K2P 576         // 520 padded to mult of 64
#define M2 640          // 520 padded to mult of 64/128

typedef unsigned short u16;
typedef short v8s __attribute__((ext_vector_type(8)));   // 8 bf16 MFMA A/B frag
typedef float v4f __attribute__((ext_vector_type(4)));   // MFMA C/D frag

__device__ __forceinline__ u16 f2bf(float f) {
  union { float f; unsigned u; } v; v.f = f;
  unsigned r = v.u + 0x7fffu + ((v.u >> 16) & 1u);   // RNE, inputs finite
  return (u16)(r >> 16);
}

__device__ __forceinline__ float fast_tanh(float x) {
  float cx = fminf(fmaxf(x, -15.f), 15.f);
  float e = __expf(2.f * cx);
  return (e - 1.f) / (e + 1.f);
}

__device__ __forceinline__ void glds(const u16* g, u16* l) {
  __builtin_amdgcn_global_load_lds((const __attribute__((address_space(1))) void*)g,
                                   (__attribute__((address_space(3))) void*)l, 16, 0, 0);
}

// ---------- prep_all: 512-thread blocks; 2 cast-rows or 8 casta2 rows ----------
// blocks [0, 8832): two A1/Wc rows each (read-once streams via nontemporal loads)
// blocks [8832, 11392): casta2 -> A2 [32][640][576] bf16 + tsum row sums
#define PREP_ROWS 8832   // 17664/2
__global__ __launch_bounds__(512) void prep_all_kernel(
    const float* __restrict__ rf, const int* __restrict__ rel,
    const float* __restrict__ relW, const float* __restrict__ temW,
    const float* __restrict__ emb, const float* __restrict__ tem,
    u16* __restrict__ A1, u16* __restrict__ Wc,
    u16* __restrict__ A2, float* __restrict__ tsum) {
  const int blk = blockIdx.x;
  const int t = threadIdx.x;
  if (blk < PREP_ROWS) {               // ---- A1 / Wc rows (2048 f32 -> bf16, + 64 K-ext)
    const int row = blk * 2 + (t >> 8);
    const int tt = t & 255;
    const float* src;
    u16* orow;
    if (row < M1) { src = rf + (size_t)row * KIN; orow = A1 + (size_t)row * KA; }
    else {
      const int n = row - M1;
      src = (n < GG) ? (relW + (size_t)n * KIN) : (temW + (size_t)(n - GG) * KIN);
      orow = Wc + (size_t)n * KA;
    }
    const v4f* p = (const v4f*)src;
    v4f a = __builtin_nontemporal_load(p + 2 * tt);
    v4f b = __builtin_nontemporal_load(p + 2 * tt + 1);
    v8s v;
    v[0] = (short)f2bf(a[0]); v[1] = (short)f2bf(a[1]);
    v[2] = (short)f2bf(a[2]); v[3] = (short)f2bf(a[3]);
    v[4] = (short)f2bf(b[0]); v[5] = (short)f2bf(b[1]);
    v[6] = (short)f2bf(b[2]); v[7] = (short)f2bf(b[3]);
    *(v8s*)(orow + tt * 8) = v;
    if (tt < 64) {                     // K-extension columns
      float sval = 0.f;
      if (row < M1) {                  // S[m,l] = count(idx==l+1)/msum
        const int* rp = rel + (size_t)row * 20;
        int cnt = 0, ms = 0;
#pragma unroll
        for (int j = 0; j < 20; ++j) { int ix = rp[j]; cnt += (ix == tt + 1); ms += (ix > 0); }
        if (tt < 52 && ms > 0) sval = (float)cnt / (float)ms;
      } else {
        const int n = row - M1;
        if (n < GG && tt < 52) sval = emb[(size_t)(tt + 1) * GG + n];
      }
      orow[KIN + tt] = f2bf(sval);
    }
    return;
  }
  // ---- casta2: tem_feats -> A2 [32][640][576] bf16 + row sums (8 rows/block)
  const int w = t >> 6, l = t & 63;
  const int row = (blk - PREP_ROWS) * 8 + w;     // [32][640]
  const int b = row / M2, i = row % M2;
  u16* orow = A2 + (size_t)row * K2P;
  v8s z = {0, 0, 0, 0, 0, 0, 0, 0};
  if (i >= FO) {
    *(v8s*)(orow + l * 8) = z;
    if (l < 8) *(v8s*)(orow + (64 + l) * 8) = z;
    return;
  }
  const float* srow = tem + ((size_t)b * FO + i) * FO;
  float s = 0.f;
  {
    v4f a = __builtin_nontemporal_load((const v4f*)(srow + 8 * l));
    v4f bb = __builtin_nontemporal_load((const v4f*)(srow + 8 * l + 4));
    s += a[0] + a[1] + a[2] + a[3] + bb[0] + bb[1] + bb[2] + bb[3];
    v8s v;
    v[0] = (short)f2bf(a[0]); v[1] = (short)f2bf(a[1]);
    v[2] = (short)f2bf(a[2]); v[3] = (short)f2bf(a[3]);
    v[4] = (short)f2bf(bb[0]); v[5] = (short)f2bf(bb[1]);
    v[6] = (short)f2bf(bb[2]); v[7] = (short)f2bf(bb[3]);
    *(v8s*)(orow + l * 8) = v;
  }
  if (l < 8) {
    if (l == 0) {
      v4f a = __builtin_nontemporal_load((const v4f*)(srow + 512));
      v4f bb = __builtin_nontemporal_load((const v4f*)(srow + 516));
      s += a[0] + a[1] + a[2] + a[3] + bb[0] + bb[1] + bb[2] + bb[3];
      v8s v;
      v[0] = (short)f2bf(a[0]); v[1] = (short)f2bf(a[1]);
      v[2] = (short)f2bf(a[2]); v[3] = (short)f2bf(a[3]);
      v[4] = (short)f2bf(bb[0]); v[5] = (short)f2bf(bb[1]);
      v[6] = (short)f2bf(bb[2]); v[7] = (short)f2bf(bb[3]);
      *(v8s*)(orow + 512) = v;
    } else {
      *(v8s*)(orow + (64 + l) * 8) = z;
    }
  }
#pragma unroll
  for (int off = 32; off > 0; off >>= 1) s += __shfl_down(s, off);
  if (l == 0) tsum[(size_t)b * FO + i] = s;
}

// ---------- GEMM1: [16640x2112]x[2112x1024] bf16 MFMA, 256x128 tile ----------
// R3/R5-proven SCHEDULE (3 LDS bufs x 24KB, BK=32, depth-2 counted-vmcnt, 2
// barriers/K-step, XOR-swizzled chunks, grid 520 = 65x8 XCD-chunked) with a
// NEW wave geometry: 256 threads / 4 waves (2m x 2n), wave tile 128x64,
// acc[8][4]. Rationale: kernel is LDS-read-BW bound (128KB frag reads/CU/
// K-step vs ~307cy MFMA); 128x64 wave reads 12KB per 32 MFMA (-25% per MFMA).
// Staging: 6 glds/thread/K-step (A rows r0+{0,64,128,192}, B rows r0+{0,64});
// LDS slot (r,sl) holds global chunk sl^((r>>1)&3) -- (r+64k) preserves the
// XOR key, so one chunk index serves all 6 pointers.
#define G1_STAGE(DST)                                                                            \
  do {                                                                                           \
    u16* dst_ = smem + (DST) + tid * 8;                                                          \
    glds(ga0, dst_);         glds(ga1, dst_ + 2048);                                             \
    glds(ga2, dst_ + 4096);  glds(ga3, dst_ + 6144);                                             \
    glds(gb0, dst_ + 8192);  glds(gb1, dst_ + 10240);                                            \
    ga0 += 32; ga1 += 32; ga2 += 32; ga3 += 32; gb0 += 32; gb1 += 32;                            \
  } while (0)

#define G1_COMPUTE(CB)                                                                           \
  do {                                                                                           \
    const u16* As_ = smem + (CB) * 12288;                                                        \
    const u16* Bs_ = As_ + 8192;                                                                 \
    v8s af[8], bf[4];                                                                            \
    _Pragma("unroll") for (int i = 0; i < 8; ++i) {                                              \
      const int ra = wm * 128 + i * 16 + r16;                                                    \
      af[i] = *(const v8s*)&As_[ra * 32 + ((quad ^ ((ra >> 1) & 3)) * 8)];                       \
    }                                                                                            \
    _Pragma("unroll") for (int j = 0; j < 4; ++j) {                                              \
      const int rb = wn * 64 + j * 16 + r16;                                                     \
      bf[j] = *(const v8s*)&Bs_[rb * 32 + ((quad ^ ((rb >> 1) & 3)) * 8)];                       \
    }                                                                                            \
    _Pragma("unroll") for (int i = 0; i < 8; ++i)                                                \
      _Pragma("unroll") for (int j = 0; j < 4; ++j)                                              \
        acc[i][j] =                                                                              \
            __builtin_amdgcn_mfma_f32_16x16x32_bf16(af[i], bf[j], acc[i][j], 0, 0, 0);           \
  } while (0)

__global__ __launch_bounds__(256, 2) void gemm1_kernel(
    const u16* __restrict__ A, const u16* __restrict__ Wc,
    const float* __restrict__ rel_b, const float* __restrict__ tem_b,
    const float* __restrict__ bn_w, const float* __restrict__ bn_b,
    const float* __restrict__ bn_rm, const float* __restrict__ bn_rv,
    float* __restrict__ out, u16* __restrict__ BT) {
  __shared__ u16 smem[36864];                     // 72KB: 3 bufs x (A 16KB | B 8KB); epi reuses 33.8KB
  const int tid = threadIdx.x;
  const int lane = tid & 63;
  const int wv = tid >> 6, wm = wv >> 1, wn = wv & 1;   // 2m x 2n waves of 128x64
  // XCD-chunked bijective swizzle: 520 % 8 == 0 -> wgid = (id%8)*65 + id/8
  const int id = blockIdx.x;
  const int wgid = (id & 7) * 65 + (id >> 3);
  const int mt = wgid >> 3, nt = wgid & 7;        // 65 x 8
  const int m0 = mt * 256, n0 = nt * 128;
  const int quad = lane >> 4, r16 = lane & 15;

  // staging pointers: r0 = tid>>2 in [0,64), chunk c0 = (sl ^ ((r0>>1)&3))*8
  const u16 *ga0, *ga1, *ga2, *ga3, *gb0, *gb1;
  {
    const int r0 = tid >> 2, sl0 = tid & 3;
    const int c0 = (sl0 ^ ((r0 >> 1) & 3)) * 8;
    ga0 = A + (size_t)(m0 + r0) * KA + c0;
    ga1 = A + (size_t)(m0 + 64 + r0) * KA + c0;
    ga2 = A + (size_t)(m0 + 128 + r0) * KA + c0;
    ga3 = A + (size_t)(m0 + 192 + r0) * KA + c0;
    gb0 = Wc + (size_t)(n0 + r0) * KA + c0;
    gb1 = Wc + (size_t)(n0 + 64 + r0) * KA + c0;
  }

  v4f acc[8][4];
#pragma unroll
  for (int i = 0; i < 8; ++i)
#pragma unroll
    for (int j = 0; j < 4; ++j) { v4f z = {0.f, 0.f, 0.f, 0.f}; acc[i][j] = z; }

  // prologue: stage K-tiles 0,1 into buffers 0,1 (12 loads in flight)
  G1_STAGE(0);
  G1_STAGE(12288);

  int cb = 0, nb = 2;                             // compute buf / next stage buf
  for (int t = 0; t < 64; ++t) {                  // tiles 0..63; stages tiles 2..65
    G1_STAGE(nb * 12288);                         // 18 loads in flight
    asm volatile("s_waitcnt vmcnt(12)" ::: "memory");  // tile t's 6 loads landed
    __builtin_amdgcn_s_barrier();                 // ...for every wave
    G1_COMPUTE(cb);
    asm volatile("s_waitcnt lgkmcnt(0)" ::: "memory");  // my ds_reads of buf cb done
    __builtin_amdgcn_s_barrier();                 // everyone done reading buf cb
    cb = (cb == 2) ? 0 : cb + 1;
    nb = (nb == 2) ? 0 : nb + 1;
  }
  {                                               // tiles 64, 65
    const int cb1 = (cb == 2) ? 0 : cb + 1;
    asm volatile("s_waitcnt vmcnt(6)" ::: "memory");
    __builtin_amdgcn_s_barrier();
    G1_COMPUTE(cb);
    asm volatile("s_waitcnt vmcnt(0) lgkmcnt(0)" ::: "memory");
    __builtin_amdgcn_s_barrier();
    G1_COMPUTE(cb1);
  }

  if (n0 < GG) {        // ---- rel half: +bias, tanh, BN -> out
#pragma unroll
    for (int mtt = 0; mtt < 8; ++mtt) {
      const int mb = m0 + wm * 128 + mtt * 16 + quad * 4;
      const int bb = mb / FO;
      const int fo0 = mb - bb * FO;               // quad never crosses batch (4 | FO)
      float inv[4], rm[4], bofs[4];
#pragma unroll
      for (int r = 0; r < 4; ++r) {
        const int fo = fo0 + r;
        inv[r] = bn_w[fo] * rsqrtf(bn_rv[fo] + 1e-5f);
        rm[r] = bn_rm[fo]; bofs[r] = bn_b[fo];
      }
#pragma unroll
      for (int ntt = 0; ntt < 4; ++ntt) {
        const int n = n0 + wn * 64 + ntt * 16 + r16;
        const float rbn = rel_b[n];
#pragma unroll
        for (int r = 0; r < 4; ++r) {
          float val = (fast_tanh(acc[mtt][ntt][r] + rbn) - rm[r]) * inv[r] + bofs[r];
          __builtin_nontemporal_store(val, out + (size_t)(mb + r) * N1 + n);
        }
      }
    }
  } else {              // ---- tem half: +bias -> bf16 -> LDS transpose -> BT (2 phases)
    __syncthreads();    // all waves done with K-loop LDS (reused as transpose buffer)
#pragma unroll
    for (int p = 0; p < 2; ++p) {
      if (p) __syncthreads();                     // phase0 readers done
      if (wn == p) {                              // 2 writer waves (wm 0,1)
#pragma unroll
        for (int mtt = 0; mtt < 8; ++mtt) {
          const int il = wm * 128 + mtt * 16 + quad * 4;  // 0..255
#pragma unroll
          for (int ntt = 0; ntt < 4; ++ntt) {
            const int gl = ntt * 16 + r16;        // local g row 0..63
            const float tb = tem_b[(n0 - GG) + p * 64 + gl];
            ushort4 w;
            w.x = f2bf(acc[mtt][ntt][0] + tb);
            w.y = f2bf(acc[mtt][ntt][1] + tb);
            w.z = f2bf(acc[mtt][ntt][2] + tb);
            w.w = f2bf(acc[mtt][ntt][3] + tb);
            *(ushort4*)&smem[gl * 264 + il] = w;  // [64 g][256 i + 8 pad]
          }
        }
      }
      __syncthreads();
      // 64 g-rows x 256 i: 8 passes x (8 g x 32 chunks), 512B contiguous stores
#pragma unroll
      for (int pass = 0; pass < 8; ++pass) {
        const int gl = pass * 8 + (tid >> 5);     // 0..63
        const int ch = tid & 31;
        const int m = m0 + ch * 8;
        const int b1 = m / FO;                    // 8-runs never cross b (520 % 8 == 0)
        const int i1 = m - b1 * FO;
        v8s val = *(const v8s*)&smem[gl * 264 + ch * 8];
        const int g = (n0 - GG) + p * 64 + gl;
        *(v8s*)(BT + ((size_t)(b1 * GG + g)) * K2P + i1) = val;
      }
    }
  }
}

// ---------- GEMM2: batched [640x576]x[576x512], 128x256 tiles ----------
// 512 threads / 8 waves (2m x 4n, wave 64x64), BK=32, same depth-2 pipeline.
// Grid (5,2,32) = 320 blocks at 2 blocks/CU -> single round.
#define G2_STAGE(DST)                                                                            \
  do {                                                                                           \
    u16* dst_ = smem + (DST);                                                                    \
    glds(ga0, dst_ + lofA0); glds(gb0, dst_ + lofB0); glds(gb1, dst_ + lofB1);                   \
    ga0 += 32; gb0 += 32; gb1 += 32;                                                             \
  } while (0)

#define G2_COMPUTE(CB)                                                                           \
  do {                                                                                           \
    const u16* As_ = smem + (CB) * 12288;                                                        \
    const u16* Bs_ = As_ + 4096;                                                                 \
    v8s af[4], bf[4];                                                                            \
    _Pragma("unroll") for (int t4 = 0; t4 < 4; ++t4) {                                           \
      const int ra = wm * 64 + t4 * 16 + r16;                                                    \
      const int rb = wn * 64 + t4 * 16 + r16;                                                    \
      af[t4] = *(const v8s*)&As_[ra * 32 + ((quad ^ ((ra >> 1) & 3)) * 8)];                      \
      bf[t4] = *(const v8s*)&Bs_[rb * 32 + ((quad ^ ((rb >> 1) & 3)) * 8)];                      \
    }                                                                                            \
    _Pragma("unroll") for (int mtt = 0; mtt < 4; ++mtt)                                          \
      _Pragma("unroll") for (int ntt = 0; ntt < 4; ++ntt)                                        \
        acc[mtt][ntt] =                                                                          \
            __builtin_amdgcn_mfma_f32_16x16x32_bf16(af[mtt], bf[ntt], acc[mtt][ntt], 0, 0, 0);   \
  } while (0)

__global__ __launch_bounds__(512, 4) void gemm2_kernel(
    const u16* __restrict__ A2, const u16* __restrict__ BT,
    const float* __restrict__ tsum,
    const float* __restrict__ bn_w, const float* __restrict__ bn_b,
    const float* __restrict__ bn_rm, const float* __restrict__ bn_rv,
    float* __restrict__ out) {
  __shared__ u16 smem[36864];                     // 72KB: 3 bufs x (A 8KB | B 16KB)
  const int tid = threadIdx.x;
  const int lane = tid & 63;
  const int wv = tid >> 6, wm = wv >> 2, wn = wv & 3;   // 2m x 4n waves of 64x64
  const int m0 = blockIdx.x * 128;                // 5 tiles over 640
  const int n0 = blockIdx.y * 256;                // 2 tiles over 512
  const int b = blockIdx.z;
  const u16* Ab = A2 + (size_t)b * M2 * K2P;
  const u16* Bb = BT + (size_t)b * GG * K2P;
  const int quad = lane >> 4, r16 = lane & 15;

  const u16 *ga0, *gb0, *gb1;
  {
    const int r0 = tid >> 2, sl0 = tid & 3;       // rows 0..127
    const int c0 = (sl0 ^ ((r0 >> 1) & 3)) * 8;
    ga0 = Ab + (size_t)(m0 + r0) * K2P + c0;                // A rows 0..127
    gb0 = Bb + (size_t)(n0 + r0) * K2P + c0;                // B rows 0..127
    gb1 = Bb + (size_t)(n0 + 128 + r0) * K2P + c0;          // B rows 128..255
  }
  const int lofA0 = wv * 512;                     // A buf [0,4096) u16
  const int lofB0 = 4096 + wv * 512;              // B buf [4096,12288) u16
  const int lofB1 = 8192 + wv * 512;

  v4f acc[4][4];
#pragma unroll
  for (int i = 0; i < 4; ++i)
#pragma unroll
    for (int j = 0; j < 4; ++j) { v4f z = {0.f, 0.f, 0.f, 0.f}; acc[i][j] = z; }

  // prologue: stage K-tiles 0,1
  G2_STAGE(0);
  G2_STAGE(12288);

  int cb = 0, nb = 2;
  for (int t = 0; t < 16; ++t) {                  // tiles 0..15; stages 2..17 (18 total)
    G2_STAGE(nb * 12288);
    asm volatile("s_waitcnt vmcnt(6)" ::: "memory");
    __builtin_amdgcn_s_barrier();
    G2_COMPUTE(cb);
    asm volatile("s_waitcnt lgkmcnt(0)" ::: "memory");
    __builtin_amdgcn_s_barrier();
    cb = (cb == 2) ? 0 : cb + 1;
    nb = (nb == 2) ? 0 : nb + 1;
  }
  {                                               // tiles 16, 17
    const int cb1 = (cb == 2) ? 0 : cb + 1;
    asm volatile("s_waitcnt vmcnt(3)" ::: "memory");
    __builtin_amdgcn_s_barrier();
    G2_COMPUTE(cb);
    asm volatile("s_waitcnt vmcnt(0) lgkmcnt(0)" ::: "memory");
    __builtin_amdgcn_s_barrier();
    G2_COMPUTE(cb1);
  }

  // epilogue: tem half of out
#pragma unroll
  for (int mtt = 0; mtt < 4; ++mtt) {
    const int ibase = m0 + wm * 64 + mtt * 16 + quad * 4;
    if (ibase >= FO) continue;                    // padded rows (ibase%4==0, FO%4==0)
    float ts[4], inv[4], rm[4], bofs[4];
#pragma unroll
    for (int r = 0; r < 4; ++r) {
      const int i = ibase + r;
      ts[r] = 1.f / tsum[(size_t)b * FO + i];
      inv[r] = bn_w[i] * rsqrtf(bn_rv[i] + 1e-5f);
      rm[r] = bn_rm[i]; bofs[r] = bn_b[i];
    }
#pragma unroll
    for (int ntt = 0; ntt < 4; ++ntt) {
      const int g = n0 + wn * 64 + ntt * 16 + r16;
#pragma unroll
      for (int r = 0; r < 4; ++r) {
        float val = (fast_tanh(acc[mtt][ntt][r] * ts[r]) - rm[r]) * inv[r] + bofs[r];
        __builtin_nontemporal_store(val, out + ((size_t)(b * FO + (ibase + r))) * N1 + GG + g);
      }
    }
  }
}

extern "C" void kernel_launch(void* const* d_in, const int* in_sizes, int n_in,
                              void* d_out, int out_size, void* d_ws, size_t ws_size,
                              hipStream_t stream) {
  const float* region_feats = (const float*)d_in[0];
  // d_in[1] region_masks: unused by reference
  const int* rel_feats = (const int*)d_in[2];
  const float* tem_feats = (const float*)d_in[3];
  const float* rel_W = (const float*)d_in[4];
  const float* rel_b = (const float*)d_in[5];
  const float* rel_emb = (const float*)d_in[6];
  const float* tem_W = (const float*)d_in[7];
  const float* tem_b = (const float*)d_in[8];
  const float* bn_w = (const float*)d_in[9];
  const float* bn_b = (const float*)d_in[10];
  const float* bn_rm = (const float*)d_in[11];
  const float* bn_rv = (const float*)d_in[12];
  float* out = (float*)d_out;

  // Workspace layout: total 117.1 MB
  char* base = (char*)d_ws;
  u16* A1 = (u16*)base;                                   // [16640][2112] bf16 : 70,287,360
  u16* Wc = (u16*)(base + 70287360);                      // [1024][2112] bf16  :  4,325,376
  u16* A2 = (u16*)(base + 74612736);                      // [32][640][576] bf16: 23,592,960
  u16* BT = (u16*)(base + 98205696);                      // [32][512][576] bf16: 18,874,368
  float* tsum = (float*)(base + 117080064);               // [32*520] f32       :     66,560

  prep_all_kernel<<<PREP_ROWS + 2560, 512, 0, stream>>>(
      region_feats, rel_feats, rel_W, tem_W, rel_emb, tem_feats, A1, Wc, A2, tsum);
  gemm1_kernel<<<520, 256, 0, stream>>>(A1, Wc, rel_b, tem_b,
                                        bn_w, bn_b, bn_rm, bn_rv, out, BT);
  gemm2_kernel<<<dim3(5, 2, 32), 512, 0, stream>>>(A2, BT, tsum,
                                                   bn_w, bn_b, bn_rm, bn_rv, out);
}

// Round 9
// 375.545 us; speedup vs baseline: 1.0606x; 1.0606x over previous
//
#include <hip/hip_runtime.h>
#include <stdint.h>

// Problem constants
#define BB 32
#define FO 520          // F*O
#define M1 16640        // BB*FO
#define KIN 2048        // IN
#define KA 2112         // IN + 64 (S-matrix columns folded into K)
#define N1 1024         // 2*G (concatenated rel|tem)
#define GG 512          // G
#define K2P 576         // 520 padded to mult of 64
#define M2 640          // 520 padded to mult of 64/128

typedef unsigned short u16;
typedef short v8s __attribute__((ext_vector_type(8)));   // 8 bf16 MFMA A/B frag
typedef float v4f __attribute__((ext_vector_type(4)));   // MFMA C/D frag

__device__ __forceinline__ u16 f2bf(float f) {
  union { float f; unsigned u; } v; v.f = f;
  unsigned r = v.u + 0x7fffu + ((v.u >> 16) & 1u);   // RNE, inputs finite
  return (u16)(r >> 16);
}

__device__ __forceinline__ float fast_tanh(float x) {
  float cx = fminf(fmaxf(x, -15.f), 15.f);
  float e = __expf(2.f * cx);
  return (e - 1.f) / (e + 1.f);
}

__device__ __forceinline__ void glds(const u16* g, u16* l) {
  __builtin_amdgcn_global_load_lds((const __attribute__((address_space(1))) void*)g,
                                   (__attribute__((address_space(3))) void*)l, 16, 0, 0);
}

// ---------- prep_all: 512-thread blocks; 2 cast-rows or 8 casta2 rows ----------
#define PREP_ROWS 8832   // 17664/2
__global__ __launch_bounds__(512) void prep_all_kernel(
    const float* __restrict__ rf, const int* __restrict__ rel,
    const float* __restrict__ relW, const float* __restrict__ temW,
    const float* __restrict__ emb, const float* __restrict__ tem,
    u16* __restrict__ A1, u16* __restrict__ Wc,
    u16* __restrict__ A2, float* __restrict__ tsum) {
  const int blk = blockIdx.x;
  const int t = threadIdx.x;
  if (blk < PREP_ROWS) {               // ---- A1 / Wc rows (2048 f32 -> bf16, + 64 K-ext)
    const int row = blk * 2 + (t >> 8);
    const int tt = t & 255;
    const float* src;
    u16* orow;
    if (row < M1) { src = rf + (size_t)row * KIN; orow = A1 + (size_t)row * KA; }
    else {
      const int n = row - M1;
      src = (n < GG) ? (relW + (size_t)n * KIN) : (temW + (size_t)(n - GG) * KIN);
      orow = Wc + (size_t)n * KA;
    }
    const v4f* p = (const v4f*)src;
    v4f a = __builtin_nontemporal_load(p + 2 * tt);
    v4f b = __builtin_nontemporal_load(p + 2 * tt + 1);
    v8s v;
    v[0] = (short)f2bf(a[0]); v[1] = (short)f2bf(a[1]);
    v[2] = (short)f2bf(a[2]); v[3] = (short)f2bf(a[3]);
    v[4] = (short)f2bf(b[0]); v[5] = (short)f2bf(b[1]);
    v[6] = (short)f2bf(b[2]); v[7] = (short)f2bf(b[3]);
    *(v8s*)(orow + tt * 8) = v;
    if (tt < 64) {                     // K-extension columns
      float sval = 0.f;
      if (row < M1) {                  // S[m,l] = count(idx==l+1)/msum
        const int* rp = rel + (size_t)row * 20;
        int cnt = 0, ms = 0;
#pragma unroll
        for (int j = 0; j < 20; ++j) { int ix = rp[j]; cnt += (ix == tt + 1); ms += (ix > 0); }
        if (tt < 52 && ms > 0) sval = (float)cnt / (float)ms;
      } else {
        const int n = row - M1;
        if (n < GG && tt < 52) sval = emb[(size_t)(tt + 1) * GG + n];
      }
      orow[KIN + tt] = f2bf(sval);
    }
    return;
  }
  // ---- casta2: tem_feats -> A2 [32][640][576] bf16 + row sums (8 rows/block)
  const int w = t >> 6, l = t & 63;
  const int row = (blk - PREP_ROWS) * 8 + w;     // [32][640]
  const int b = row / M2, i = row % M2;
  u16* orow = A2 + (size_t)row * K2P;
  v8s z = {0, 0, 0, 0, 0, 0, 0, 0};
  if (i >= FO) {
    *(v8s*)(orow + l * 8) = z;
    if (l < 8) *(v8s*)(orow + (64 + l) * 8) = z;
    return;
  }
  const float* srow = tem + ((size_t)b * FO + i) * FO;
  float s = 0.f;
  {
    v4f a = __builtin_nontemporal_load((const v4f*)(srow + 8 * l));
    v4f bb = __builtin_nontemporal_load((const v4f*)(srow + 8 * l + 4));
    s += a[0] + a[1] + a[2] + a[3] + bb[0] + bb[1] + bb[2] + bb[3];
    v8s v;
    v[0] = (short)f2bf(a[0]); v[1] = (short)f2bf(a[1]);
    v[2] = (short)f2bf(a[2]); v[3] = (short)f2bf(a[3]);
    v[4] = (short)f2bf(bb[0]); v[5] = (short)f2bf(bb[1]);
    v[6] = (short)f2bf(bb[2]); v[7] = (short)f2bf(bb[3]);
    *(v8s*)(orow + l * 8) = v;
  }
  if (l < 8) {
    if (l == 0) {
      v4f a = __builtin_nontemporal_load((const v4f*)(srow + 512));
      v4f bb = __builtin_nontemporal_load((const v4f*)(srow + 516));
      s += a[0] + a[1] + a[2] + a[3] + bb[0] + bb[1] + bb[2] + bb[3];
      v8s v;
      v[0] = (short)f2bf(a[0]); v[1] = (short)f2bf(a[1]);
      v[2] = (short)f2bf(a[2]); v[3] = (short)f2bf(a[3]);
      v[4] = (short)f2bf(bb[0]); v[5] = (short)f2bf(bb[1]);
      v[6] = (short)f2bf(bb[2]); v[7] = (short)f2bf(bb[3]);
      *(v8s*)(orow + 512) = v;
    } else {
      *(v8s*)(orow + (64 + l) * 8) = z;
    }
  }
#pragma unroll
  for (int off = 32; off > 0; off >>= 1) s += __shfl_down(s, off);
  if (l == 0) tsum[(size_t)b * FO + i] = s;
}

// ---------- GEMM1: [16640x2112]x[2112x1024] bf16 MFMA ----------
// R5-proven schedule (BK=32, 3 LDS buffers, depth-2 counted-vmcnt, 2 barriers/
// K-step, XOR-swizzled chunks, 512 threads / 8 waves 4m x 2n), templated on G =
// A-row groups: G=2 -> 256x128 tile (byte-identical to R5), G=1 -> 128x128.
// Grid 528: ids [0,512) = fulls over rows [0,16384) (XCD-chunked swizzle, fills
// all 512 block slots at 2/CU in ONE round); ids [512,528) = 16 half tiles over
// rows [16384,16640). Straggler round shrinks from T_full to T_full/2
// (makespan 2T -> 1.5T; R5/R8 occupancy showed ~48% of kernel time was the
// 8-block tail running nearly alone).
template <int G>
__device__ __forceinline__ void gemm1_body(
    const u16* __restrict__ A, const u16* __restrict__ Wc,
    const float* __restrict__ rel_b, const float* __restrict__ tem_b,
    const float* __restrict__ bn_w, const float* __restrict__ bn_b,
    const float* __restrict__ bn_rm, const float* __restrict__ bn_rv,
    float* __restrict__ out, u16* __restrict__ BT, u16* smem,
    const int m0, const int n0) {
  constexpr int SB = (G + 1) * 4096;              // LDS buffer stride (u16)
  const int tid = threadIdx.x;
  const int lane = tid & 63;
  const int wv = tid >> 6, wm = wv >> 1, wn = wv & 1;   // 4m x 2n waves
  const int quad = lane >> 4, r16 = lane & 15;

  // staging: chunk (row r, slot sl) holds global chunk c = sl ^ ((r>>1)&3)
  const u16 *ga0, *ga1 = nullptr, *gb0;
  {
    const int r0 = tid >> 2, sl0 = tid & 3;       // rows 0..127
    const int c0 = (sl0 ^ ((r0 >> 1) & 3)) * 8;
    ga0 = A + (size_t)(m0 + r0) * KA + c0;
    if constexpr (G == 2) ga1 = A + (size_t)(m0 + 128 + r0) * KA + c0;
    gb0 = Wc + (size_t)(n0 + r0) * KA + c0;
  }
  const int lofA0 = wv * 512;
  const int lofA1 = 4096 + wv * 512;              // G==2 only
  const int lofB0 = G * 4096 + wv * 512;

  auto STAGE = [&](int dstoff) {
    u16* dst_ = smem + dstoff;
    glds(ga0, dst_ + lofA0);
    if constexpr (G == 2) { glds(ga1, dst_ + lofA1); ga1 += 32; }
    glds(gb0, dst_ + lofB0);
    ga0 += 32; gb0 += 32;
  };

  v4f acc[2 * G][4];
#pragma unroll
  for (int i = 0; i < 2 * G; ++i)
#pragma unroll
    for (int j = 0; j < 4; ++j) { v4f z = {0.f, 0.f, 0.f, 0.f}; acc[i][j] = z; }

  auto COMPUTE = [&](int cbuf) {
    const u16* As_ = smem + cbuf * SB;
    const u16* Bs_ = As_ + G * 4096;
    v8s af[2 * G], bf[4];
#pragma unroll
    for (int i = 0; i < 2 * G; ++i) {
      const int ra = wm * (G * 32) + i * 16 + r16;
      af[i] = *(const v8s*)&As_[ra * 32 + ((quad ^ ((ra >> 1) & 3)) * 8)];
    }
#pragma unroll
    for (int j = 0; j < 4; ++j) {
      const int rb = wn * 64 + j * 16 + r16;
      bf[j] = *(const v8s*)&Bs_[rb * 32 + ((quad ^ ((rb >> 1) & 3)) * 8)];
    }
#pragma unroll
    for (int i = 0; i < 2 * G; ++i)
#pragma unroll
      for (int j = 0; j < 4; ++j)
        acc[i][j] = __builtin_amdgcn_mfma_f32_16x16x32_bf16(af[i], bf[j], acc[i][j], 0, 0, 0);
  };

  // prologue: stage K-tiles 0,1 into buffers 0,1
  STAGE(0);
  STAGE(SB);

  int cb = 0, nb = 2;                             // compute buf / next stage buf
  for (int t = 0; t < 64; ++t) {                  // tiles 0..63; stages tiles 2..65
    STAGE(nb * SB);
    if constexpr (G == 2) asm volatile("s_waitcnt vmcnt(6)" ::: "memory");
    else                  asm volatile("s_waitcnt vmcnt(4)" ::: "memory");
    __builtin_amdgcn_s_barrier();                 // oldest tile landed for all
    COMPUTE(cb);
    asm volatile("s_waitcnt lgkmcnt(0)" ::: "memory");  // my ds_reads done
    __builtin_amdgcn_s_barrier();                 // everyone done reading buf cb
    cb = (cb == 2) ? 0 : cb + 1;
    nb = (nb == 2) ? 0 : nb + 1;
  }
  {                                               // tiles 64, 65
    const int cb1 = (cb == 2) ? 0 : cb + 1;
    if constexpr (G == 2) asm volatile("s_waitcnt vmcnt(3)" ::: "memory");
    else                  asm volatile("s_waitcnt vmcnt(2)" ::: "memory");
    __builtin_amdgcn_s_barrier();
    COMPUTE(cb);
    asm volatile("s_waitcnt vmcnt(0) lgkmcnt(0)" ::: "memory");
    __builtin_amdgcn_s_barrier();
    COMPUTE(cb1);
  }

  if (n0 < GG) {        // ---- rel half: +bias, tanh, BN -> out
#pragma unroll
    for (int mtt = 0; mtt < 2 * G; ++mtt) {
      const int mb = m0 + wm * (G * 32) + mtt * 16 + quad * 4;
      const int bb = mb / FO;
      const int fo0 = mb - bb * FO;               // quad never crosses batch (4 | FO)
      float inv[4], rm[4], bofs[4];
#pragma unroll
      for (int r = 0; r < 4; ++r) {
        const int fo = fo0 + r;
        inv[r] = bn_w[fo] * rsqrtf(bn_rv[fo] + 1e-5f);
        rm[r] = bn_rm[fo]; bofs[r] = bn_b[fo];
      }
#pragma unroll
      for (int ntt = 0; ntt < 4; ++ntt) {
        const int n = n0 + wn * 64 + ntt * 16 + r16;
        const float rbn = rel_b[n];
#pragma unroll
        for (int r = 0; r < 4; ++r) {
          float val = (fast_tanh(acc[mtt][ntt][r] + rbn) - rm[r]) * inv[r] + bofs[r];
          __builtin_nontemporal_store(val, out + (size_t)(mb + r) * N1 + n);
        }
      }
    }
  } else {              // ---- tem half: +bias -> bf16 -> LDS transpose -> BT
    constexpr int SP = G * 128 + 8;               // transpose row stride (u16)
    __syncthreads();                              // K-loop LDS reads all done
#pragma unroll
    for (int p = 0; p < 2; ++p) {
      if (p) __syncthreads();                     // phase0 readers done
      if (wn == p) {                              // 4 writer waves (wm 0..3)
#pragma unroll
        for (int mtt = 0; mtt < 2 * G; ++mtt) {
          const int il = wm * (G * 32) + mtt * 16 + quad * 4;   // 0..G*128
#pragma unroll
          for (int ntt = 0; ntt < 4; ++ntt) {
            const int gl = ntt * 16 + r16;        // local g row 0..63
            const float tb = tem_b[(n0 - GG) + p * 64 + gl];
            ushort4 w;
            w.x = f2bf(acc[mtt][ntt][0] + tb);
            w.y = f2bf(acc[mtt][ntt][1] + tb);
            w.z = f2bf(acc[mtt][ntt][2] + tb);
            w.w = f2bf(acc[mtt][ntt][3] + tb);
            *(ushort4*)&smem[gl * SP + il] = w;
          }
        }
      }
      __syncthreads();
      // copy out 64 g x (G*128) i, 8-elem contiguous chunks
      if constexpr (G == 2) {
#pragma unroll
        for (int pass = 0; pass < 4; ++pass) {
          const int gl = pass * 16 + (tid >> 5);  // 0..63
          const int ch = tid & 31;
          const int m = m0 + ch * 8;
          const int b1 = m / FO;                  // 8-runs never cross b (520%8==0)
          const int i1 = m - b1 * FO;
          v8s val = *(const v8s*)&smem[gl * SP + ch * 8];
          const int g = (n0 - GG) + p * 64 + gl;
          *(v8s*)(BT + ((size_t)(b1 * GG + g)) * K2P + i1) = val;
        }
      } else {
#pragma unroll
        for (int pass = 0; pass < 2; ++pass) {
          const int gl = pass * 32 + (tid >> 4);  // 0..63
          const int ch = tid & 15;
          const int m = m0 + ch * 8;
          const int b1 = m / FO;
          const int i1 = m - b1 * FO;
          v8s val = *(const v8s*)&smem[gl * SP + ch * 8];
          const int g = (n0 - GG) + p * 64 + gl;
          *(v8s*)(BT + ((size_t)(b1 * GG + g)) * K2P + i1) = val;
        }
      }
    }
  }
}

__global__ __launch_bounds__(512, 4) void gemm1_kernel(
    const u16* __restrict__ A, const u16* __restrict__ Wc,
    const float* __restrict__ rel_b, const float* __restrict__ tem_b,
    const float* __restrict__ bn_w, const float* __restrict__ bn_b,
    const float* __restrict__ bn_rm, const float* __restrict__ bn_rv,
    float* __restrict__ out, u16* __restrict__ BT) {
  __shared__ u16 smem[36864];                     // 72KB (G=2: 3 x 24KB; epi 33.8KB)
  const int id = blockIdx.x;
  if (id < 512) {                                 // 64 m-panels x 8 n, XCD-chunked
    const int wgid = (id & 7) * 64 + (id >> 3);   // 512 % 8 == 0 -> bijective
    gemm1_body<2>(A, Wc, rel_b, tem_b, bn_w, bn_b, bn_rm, bn_rv, out, BT, smem,
                  (wgid >> 3) * 256, (wgid & 7) * 128);
  } else {                                        // 65th panel: 2 x 8 half tiles
    const int sid = id - 512;
    gemm1_body<1>(A, Wc, rel_b, tem_b, bn_w, bn_b, bn_rm, bn_rv, out, BT, smem,
                  16384 + (sid >> 3) * 128, (sid & 7) * 128);
  }
}

// ---------- GEMM2: batched [640x576]x[576x512], 128x256 tiles ----------
// 512 threads / 8 waves (2m x 4n, wave 64x64), BK=32, same depth-2 pipeline.
// Grid (5,2,32) = 320 blocks at 2 blocks/CU -> single round.
#define G2_STAGE(DST)                                                                            \
  do {                                                                                           \
    u16* dst_ = smem + (DST);                                                                    \
    glds(ga0, dst_ + lofA0); glds(gb0, dst_ + lofB0); glds(gb1, dst_ + lofB1);                   \
    ga0 += 32; gb0 += 32; gb1 += 32;                                                             \
  } while (0)

#define G2_COMPUTE(CB)                                                                           \
  do {                                                                                           \
    const u16* As_ = smem + (CB) * 12288;                                                        \
    const u16* Bs_ = As_ + 4096;                                                                 \
    v8s af[4], bf[4];                                                                            \
    _Pragma("unroll") for (int t4 = 0; t4 < 4; ++t4) {                                           \
      const int ra = wm * 64 + t4 * 16 + r16;                                                    \
      const int rb = wn * 64 + t4 * 16 + r16;                                                    \
      af[t4] = *(const v8s*)&As_[ra * 32 + ((quad ^ ((ra >> 1) & 3)) * 8)];                      \
      bf[t4] = *(const v8s*)&Bs_[rb * 32 + ((quad ^ ((rb >> 1) & 3)) * 8)];                      \
    }                                                                                            \
    _Pragma("unroll") for (int mtt = 0; mtt < 4; ++mtt)                                          \
      _Pragma("unroll") for (int ntt = 0; ntt < 4; ++ntt)                                        \
        acc[mtt][ntt] =                                                                          \
            __builtin_amdgcn_mfma_f32_16x16x32_bf16(af[mtt], bf[ntt], acc[mtt][ntt], 0, 0, 0);   \
  } while (0)

__global__ __launch_bounds__(512, 4) void gemm2_kernel(
    const u16* __restrict__ A2, const u16* __restrict__ BT,
    const float* __restrict__ tsum,
    const float* __restrict__ bn_w, const float* __restrict__ bn_b,
    const float* __restrict__ bn_rm, const float* __restrict__ bn_rv,
    float* __restrict__ out) {
  __shared__ u16 smem[36864];                     // 72KB: 3 bufs x (A 8KB | B 16KB)
  const int tid = threadIdx.x;
  const int lane = tid & 63;
  const int wv = tid >> 6, wm = wv >> 2, wn = wv & 3;   // 2m x 4n waves of 64x64
  const int m0 = blockIdx.x * 128;                // 5 tiles over 640
  const int n0 = blockIdx.y * 256;                // 2 tiles over 512
  const int b = blockIdx.z;
  const u16* Ab = A2 + (size_t)b * M2 * K2P;
  const u16* Bb = BT + (size_t)b * GG * K2P;
  const int quad = lane >> 4, r16 = lane & 15;

  const u16 *ga0, *gb0, *gb1;
  {
    const int r0 = tid >> 2, sl0 = tid & 3;       // rows 0..127
    const int c0 = (sl0 ^ ((r0 >> 1) & 3)) * 8;
    ga0 = Ab + (size_t)(m0 + r0) * K2P + c0;                // A rows 0..127
    gb0 = Bb + (size_t)(n0 + r0) * K2P + c0;                // B rows 0..127
    gb1 = Bb + (size_t)(n0 + 128 + r0) * K2P + c0;          // B rows 128..255
  }
  const int lofA0 = wv * 512;                     // A buf [0,4096) u16
  const int lofB0 = 4096 + wv * 512;              // B buf [4096,12288) u16
  const int lofB1 = 8192 + wv * 512;

  v4f acc[4][4];
#pragma unroll
  for (int i = 0; i < 4; ++i)
#pragma unroll
    for (int j = 0; j < 4; ++j) { v4f z = {0.f, 0.f, 0.f, 0.f}; acc[i][j] = z; }

  // prologue: stage K-tiles 0,1
  G2_STAGE(0);
  G2_STAGE(12288);

  int cb = 0, nb = 2;
  for (int t = 0; t < 16; ++t) {                  // tiles 0..15; stages 2..17 (18 total)
    G2_STAGE(nb * 12288);
    asm volatile("s_waitcnt vmcnt(6)" ::: "memory");
    __builtin_amdgcn_s_barrier();
    G2_COMPUTE(cb);
    asm volatile("s_waitcnt lgkmcnt(0)" ::: "memory");
    __builtin_amdgcn_s_barrier();
    cb = (cb == 2) ? 0 : cb + 1;
    nb = (nb == 2) ? 0 : nb + 1;
  }
  {                                               // tiles 16, 17
    const int cb1 = (cb == 2) ? 0 : cb + 1;
    asm volatile("s_waitcnt vmcnt(3)" ::: "memory");
    __builtin_amdgcn_s_barrier();
    G2_COMPUTE(cb);
    asm volatile("s_waitcnt vmcnt(0) lgkmcnt(0)" ::: "memory");
    __builtin_amdgcn_s_barrier();
    G2_COMPUTE(cb1);
  }

  // epilogue: tem half of out
#pragma unroll
  for (int mtt = 0; mtt < 4; ++mtt) {
    const int ibase = m0 + wm * 64 + mtt * 16 + quad * 4;
    if (ibase >= FO) continue;                    // padded rows (ibase%4==0, FO%4==0)
    float ts[4], inv[4], rm[4], bofs[4];
#pragma unroll
    for (int r = 0; r < 4; ++r) {
      const int i = ibase + r;
      ts[r] = 1.f / tsum[(size_t)b * FO + i];
      inv[r] = bn_w[i] * rsqrtf(bn_rv[i] + 1e-5f);
      rm[r] = bn_rm[i]; bofs[r] = bn_b[i];
    }
#pragma unroll
    for (int ntt = 0; ntt < 4; ++ntt) {
      const int g = n0 + wn * 64 + ntt * 16 + r16;
#pragma unroll
      for (int r = 0; r < 4; ++r) {
        float val = (fast_tanh(acc[mtt][ntt][r] * ts[r]) - rm[r]) * inv[r] + bofs[r];
        __builtin_nontemporal_store(val, out + ((size_t)(b * FO + (ibase + r))) * N1 + GG + g);
      }
    }
  }
}

extern "C" void kernel_launch(void* const* d_in, const int* in_sizes, int n_in,
                              void* d_out, int out_size, void* d_ws, size_t ws_size,
                              hipStream_t stream) {
  const float* region_feats = (const float*)d_in[0];
  // d_in[1] region_masks: unused by reference
  const int* rel_feats = (const int*)d_in[2];
  const float* tem_feats = (const float*)d_in[3];
  const float* rel_W = (const float*)d_in[4];
  const float* rel_b = (const float*)d_in[5];
  const float* rel_emb = (const float*)d_in[6];
  const float* tem_W = (const float*)d_in[7];
  const float* tem_b = (const float*)d_in[8];
  const float* bn_w = (const float*)d_in[9];
  const float* bn_b = (const float*)d_in[10];
  const float* bn_rm = (const float*)d_in[11];
  const float* bn_rv = (const float*)d_in[12];
  float* out = (float*)d_out;

  // Workspace layout: total 117.1 MB
  char* base = (char*)d_ws;
  u16* A1 = (u16*)base;                                   // [16640][2112] bf16 : 70,287,360
  u16* Wc = (u16*)(base + 70287360);                      // [1024][2112] bf16  :  4,325,376
  u16* A2 = (u16*)(base + 74612736);                      // [32][640][576] bf16: 23,592,960
  u16* BT = (u16*)(base + 98205696);                      // [32][512][576] bf16: 18,874,368
  float* tsum = (float*)(base + 117080064);               // [32*520] f32       :     66,560

  prep_all_kernel<<<PREP_ROWS + 2560, 512, 0, stream>>>(
      region_feats, rel_feats, rel_W, tem_W, rel_emb, tem_feats, A1, Wc, A2, tsum);
  gemm1_kernel<<<528, 512, 0, stream>>>(A1, Wc, rel_b, tem_b,
                                        bn_w, bn_b, bn_rm, bn_rv, out, BT);
  gemm2_kernel<<<dim3(5, 2, 32), 512, 0, stream>>>(A2, BT, tsum,
                                                   bn_w, bn_b, bn_rm, bn_rv, out);
}

// Round 10
// 373.323 us; speedup vs baseline: 1.0669x; 1.0060x over previous
//
#include <hip/hip_runtime.h>
#include <stdint.h>

// Problem constants
#define BB 32
#define FO 520          // F*O
#define M1 16640        // BB*FO
#define KIN 2048        // IN
#define KA 2112         // IN + 64 (S-matrix columns folded into K)
#define N1 1024         // 2*G (concatenated rel|tem)
#define GG 512          // G
#define K2P 576         // 520 padded to mult of 64
#define M2 640          // 520 padded to mult of 64/128

typedef unsigned short u16;
typedef short v8s __attribute__((ext_vector_type(8)));   // 8 bf16 MFMA A/B frag
typedef float v4f __attribute__((ext_vector_type(4)));   // MFMA C/D frag

__device__ __forceinline__ u16 f2bf(float f) {
  union { float f; unsigned u; } v; v.f = f;
  unsigned r = v.u + 0x7fffu + ((v.u >> 16) & 1u);   // RNE, inputs finite
  return (u16)(r >> 16);
}

__device__ __forceinline__ float fast_tanh(float x) {
  float cx = fminf(fmaxf(x, -15.f), 15.f);
  float e = __expf(2.f * cx);
  return (e - 1.f) / (e + 1.f);
}

__device__ __forceinline__ void glds(const u16* g, u16* l) {
  __builtin_amdgcn_global_load_lds((const __attribute__((address_space(1))) void*)g,
                                   (__attribute__((address_space(3))) void*)l, 16, 0, 0);
}

// ---------- prep_all: 512-thread blocks; 2 cast-rows or 8 casta2 rows ----------
#define PREP_ROWS 8832   // 17664/2
__global__ __launch_bounds__(512) void prep_all_kernel(
    const float* __restrict__ rf, const int* __restrict__ rel,
    const float* __restrict__ relW, const float* __restrict__ temW,
    const float* __restrict__ emb, const float* __restrict__ tem,
    u16* __restrict__ A1, u16* __restrict__ Wc,
    u16* __restrict__ A2, float* __restrict__ tsum) {
  const int blk = blockIdx.x;
  const int t = threadIdx.x;
  if (blk < PREP_ROWS) {               // ---- A1 / Wc rows (2048 f32 -> bf16, + 64 K-ext)
    const int row = blk * 2 + (t >> 8);
    const int tt = t & 255;
    const float* src;
    u16* orow;
    if (row < M1) { src = rf + (size_t)row * KIN; orow = A1 + (size_t)row * KA; }
    else {
      const int n = row - M1;
      src = (n < GG) ? (relW + (size_t)n * KIN) : (temW + (size_t)(n - GG) * KIN);
      orow = Wc + (size_t)n * KA;
    }
    const v4f* p = (const v4f*)src;
    v4f a = __builtin_nontemporal_load(p + 2 * tt);
    v4f b = __builtin_nontemporal_load(p + 2 * tt + 1);
    v8s v;
    v[0] = (short)f2bf(a[0]); v[1] = (short)f2bf(a[1]);
    v[2] = (short)f2bf(a[2]); v[3] = (short)f2bf(a[3]);
    v[4] = (short)f2bf(b[0]); v[5] = (short)f2bf(b[1]);
    v[6] = (short)f2bf(b[2]); v[7] = (short)f2bf(b[3]);
    *(v8s*)(orow + tt * 8) = v;
    if (tt < 64) {                     // K-extension columns
      float sval = 0.f;
      if (row < M1) {                  // S[m,l] = count(idx==l+1)/msum
        const int* rp = rel + (size_t)row * 20;
        int cnt = 0, ms = 0;
#pragma unroll
        for (int j = 0; j < 20; ++j) { int ix = rp[j]; cnt += (ix == tt + 1); ms += (ix > 0); }
        if (tt < 52 && ms > 0) sval = (float)cnt / (float)ms;
      } else {
        const int n = row - M1;
        if (n < GG && tt < 52) sval = emb[(size_t)(tt + 1) * GG + n];
      }
      orow[KIN + tt] = f2bf(sval);
    }
    return;
  }
  // ---- casta2: tem_feats -> A2 [32][640][576] bf16 + row sums (8 rows/block)
  const int w = t >> 6, l = t & 63;
  const int row = (blk - PREP_ROWS) * 8 + w;     // [32][640]
  const int b = row / M2, i = row % M2;
  u16* orow = A2 + (size_t)row * K2P;
  v8s z = {0, 0, 0, 0, 0, 0, 0, 0};
  if (i >= FO) {
    *(v8s*)(orow + l * 8) = z;
    if (l < 8) *(v8s*)(orow + (64 + l) * 8) = z;
    return;
  }
  const float* srow = tem + ((size_t)b * FO + i) * FO;
  float s = 0.f;
  {
    v4f a = __builtin_nontemporal_load((const v4f*)(srow + 8 * l));
    v4f bb = __builtin_nontemporal_load((const v4f*)(srow + 8 * l + 4));
    s += a[0] + a[1] + a[2] + a[3] + bb[0] + bb[1] + bb[2] + bb[3];
    v8s v;
    v[0] = (short)f2bf(a[0]); v[1] = (short)f2bf(a[1]);
    v[2] = (short)f2bf(a[2]); v[3] = (short)f2bf(a[3]);
    v[4] = (short)f2bf(bb[0]); v[5] = (short)f2bf(bb[1]);
    v[6] = (short)f2bf(bb[2]); v[7] = (short)f2bf(bb[3]);
    *(v8s*)(orow + l * 8) = v;
  }
  if (l < 8) {
    if (l == 0) {
      v4f a = __builtin_nontemporal_load((const v4f*)(srow + 512));
      v4f bb = __builtin_nontemporal_load((const v4f*)(srow + 516));
      s += a[0] + a[1] + a[2] + a[3] + bb[0] + bb[1] + bb[2] + bb[3];
      v8s v;
      v[0] = (short)f2bf(a[0]); v[1] = (short)f2bf(a[1]);
      v[2] = (short)f2bf(a[2]); v[3] = (short)f2bf(a[3]);
      v[4] = (short)f2bf(bb[0]); v[5] = (short)f2bf(bb[1]);
      v[6] = (short)f2bf(bb[2]); v[7] = (short)f2bf(bb[3]);
      *(v8s*)(orow + 512) = v;
    } else {
      *(v8s*)(orow + (64 + l) * 8) = z;
    }
  }
#pragma unroll
  for (int off = 32; off > 0; off >>= 1) s += __shfl_down(s, off);
  if (l == 0) tsum[(size_t)b * FO + i] = s;
}

// ---------- GEMM1: [16640x2112]x[2112x1024] bf16 MFMA ----------
// R5/R9-proven schedule (BK=32, 3 LDS buffers, depth-2 counted-vmcnt, 2
// barriers/K-step, XOR-swizzled chunks, 512 threads / 8 waves 4m x 2n).
// G = A-row groups: G=2 -> 256x128 tile, G=1 -> 128x128.
// Grid (split-K mode) 608: ids [0,512) fulls over rows [0,16384) (one full
// round at 2 blocks/CU); ids [512,608) = 16 half-tiles x 6 K-splits of the
// 65th panel, 11 K-steps each (R9 showed the tail block is LATENCY-bound:
// 128x128 full-K took 41us ~= 0.76x a full 256x128 -> only split-K shortens
// the serial chain). Partials (f32, fragment-layout) -> tail_finish reduces.
template <int G>
__device__ __forceinline__ void gemm1_body(
    const u16* __restrict__ A, const u16* __restrict__ Wc,
    const float* __restrict__ rel_b, const float* __restrict__ tem_b,
    const float* __restrict__ bn_w, const float* __restrict__ bn_b,
    const float* __restrict__ bn_rm, const float* __restrict__ bn_rv,
    float* __restrict__ out, u16* __restrict__ BT, u16* smem,
    const int m0, const int n0) {
  constexpr int SB = (G + 1) * 4096;              // LDS buffer stride (u16)
  const int tid = threadIdx.x;
  const int lane = tid & 63;
  const int wv = tid >> 6, wm = wv >> 1, wn = wv & 1;   // 4m x 2n waves
  const int quad = lane >> 4, r16 = lane & 15;

  const u16 *ga0, *ga1 = nullptr, *gb0;
  {
    const int r0 = tid >> 2, sl0 = tid & 3;       // rows 0..127
    const int c0 = (sl0 ^ ((r0 >> 1) & 3)) * 8;
    ga0 = A + (size_t)(m0 + r0) * KA + c0;
    if constexpr (G == 2) ga1 = A + (size_t)(m0 + 128 + r0) * KA + c0;
    gb0 = Wc + (size_t)(n0 + r0) * KA + c0;
  }
  const int lofA0 = wv * 512;
  const int lofA1 = 4096 + wv * 512;              // G==2 only
  const int lofB0 = G * 4096 + wv * 512;

  auto STAGE = [&](int dstoff) {
    u16* dst_ = smem + dstoff;
    glds(ga0, dst_ + lofA0);
    if constexpr (G == 2) { glds(ga1, dst_ + lofA1); ga1 += 32; }
    glds(gb0, dst_ + lofB0);
    ga0 += 32; gb0 += 32;
  };

  v4f acc[2 * G][4];
#pragma unroll
  for (int i = 0; i < 2 * G; ++i)
#pragma unroll
    for (int j = 0; j < 4; ++j) { v4f z = {0.f, 0.f, 0.f, 0.f}; acc[i][j] = z; }

  auto COMPUTE = [&](int cbuf) {
    const u16* As_ = smem + cbuf * SB;
    const u16* Bs_ = As_ + G * 4096;
    v8s af[2 * G], bf[4];
#pragma unroll
    for (int i = 0; i < 2 * G; ++i) {
      const int ra = wm * (G * 32) + i * 16 + r16;
      af[i] = *(const v8s*)&As_[ra * 32 + ((quad ^ ((ra >> 1) & 3)) * 8)];
    }
#pragma unroll
    for (int j = 0; j < 4; ++j) {
      const int rb = wn * 64 + j * 16 + r16;
      bf[j] = *(const v8s*)&Bs_[rb * 32 + ((quad ^ ((rb >> 1) & 3)) * 8)];
    }
#pragma unroll
    for (int i = 0; i < 2 * G; ++i)
#pragma unroll
      for (int j = 0; j < 4; ++j)
        acc[i][j] = __builtin_amdgcn_mfma_f32_16x16x32_bf16(af[i], bf[j], acc[i][j], 0, 0, 0);
  };

  STAGE(0);
  STAGE(SB);

  int cb = 0, nb = 2;
  for (int t = 0; t < 64; ++t) {                  // tiles 0..63; stages tiles 2..65
    STAGE(nb * SB);
    if constexpr (G == 2) asm volatile("s_waitcnt vmcnt(6)" ::: "memory");
    else                  asm volatile("s_waitcnt vmcnt(4)" ::: "memory");
    __builtin_amdgcn_s_barrier();
    COMPUTE(cb);
    asm volatile("s_waitcnt lgkmcnt(0)" ::: "memory");
    __builtin_amdgcn_s_barrier();
    cb = (cb == 2) ? 0 : cb + 1;
    nb = (nb == 2) ? 0 : nb + 1;
  }
  {                                               // tiles 64, 65
    const int cb1 = (cb == 2) ? 0 : cb + 1;
    if constexpr (G == 2) asm volatile("s_waitcnt vmcnt(3)" ::: "memory");
    else                  asm volatile("s_waitcnt vmcnt(2)" ::: "memory");
    __builtin_amdgcn_s_barrier();
    COMPUTE(cb);
    asm volatile("s_waitcnt vmcnt(0) lgkmcnt(0)" ::: "memory");
    __builtin_amdgcn_s_barrier();
    COMPUTE(cb1);
  }

  if (n0 < GG) {        // ---- rel half: +bias, tanh, BN -> out
#pragma unroll
    for (int mtt = 0; mtt < 2 * G; ++mtt) {
      const int mb = m0 + wm * (G * 32) + mtt * 16 + quad * 4;
      const int bb = mb / FO;
      const int fo0 = mb - bb * FO;               // quad never crosses batch (4 | FO)
      float inv[4], rm[4], bofs[4];
#pragma unroll
      for (int r = 0; r < 4; ++r) {
        const int fo = fo0 + r;
        inv[r] = bn_w[fo] * rsqrtf(bn_rv[fo] + 1e-5f);
        rm[r] = bn_rm[fo]; bofs[r] = bn_b[fo];
      }
#pragma unroll
      for (int ntt = 0; ntt < 4; ++ntt) {
        const int n = n0 + wn * 64 + ntt * 16 + r16;
        const float rbn = rel_b[n];
#pragma unroll
        for (int r = 0; r < 4; ++r) {
          float val = (fast_tanh(acc[mtt][ntt][r] + rbn) - rm[r]) * inv[r] + bofs[r];
          __builtin_nontemporal_store(val, out + (size_t)(mb + r) * N1 + n);
        }
      }
    }
  } else {              // ---- tem half: +bias -> bf16 -> LDS transpose -> BT
    constexpr int SP = G * 128 + 8;               // transpose row stride (u16)
    __syncthreads();
#pragma unroll
    for (int p = 0; p < 2; ++p) {
      if (p) __syncthreads();
      if (wn == p) {
#pragma unroll
        for (int mtt = 0; mtt < 2 * G; ++mtt) {
          const int il = wm * (G * 32) + mtt * 16 + quad * 4;
#pragma unroll
          for (int ntt = 0; ntt < 4; ++ntt) {
            const int gl = ntt * 16 + r16;
            const float tb = tem_b[(n0 - GG) + p * 64 + gl];
            ushort4 w;
            w.x = f2bf(acc[mtt][ntt][0] + tb);
            w.y = f2bf(acc[mtt][ntt][1] + tb);
            w.z = f2bf(acc[mtt][ntt][2] + tb);
            w.w = f2bf(acc[mtt][ntt][3] + tb);
            *(ushort4*)&smem[gl * SP + il] = w;
          }
        }
      }
      __syncthreads();
      if constexpr (G == 2) {
#pragma unroll
        for (int pass = 0; pass < 4; ++pass) {
          const int gl = pass * 16 + (tid >> 5);
          const int ch = tid & 31;
          const int m = m0 + ch * 8;
          const int b1 = m / FO;
          const int i1 = m - b1 * FO;
          v8s val = *(const v8s*)&smem[gl * SP + ch * 8];
          const int g = (n0 - GG) + p * 64 + gl;
          *(v8s*)(BT + ((size_t)(b1 * GG + g)) * K2P + i1) = val;
        }
      } else {
#pragma unroll
        for (int pass = 0; pass < 2; ++pass) {
          const int gl = pass * 32 + (tid >> 4);
          const int ch = tid & 15;
          const int m = m0 + ch * 8;
          const int b1 = m / FO;
          const int i1 = m - b1 * FO;
          v8s val = *(const v8s*)&smem[gl * SP + ch * 8];
          const int g = (n0 - GG) + p * 64 + gl;
          *(v8s*)(BT + ((size_t)(b1 * GG + g)) * K2P + i1) = val;
        }
      }
    }
  }
}

// split-K partial: 128x128 tile, K window [k0, k0+352) = 11 BK=32 steps.
// Same G=1 pipeline; stores raw f32 acc fragments (wave-contiguous) to pb.
__device__ __forceinline__ void gemm1_partial(
    const u16* __restrict__ A, const u16* __restrict__ Wc,
    float* __restrict__ pb, u16* smem, const int m0, const int n0, const int k0) {
  constexpr int SB = 8192;                        // G=1 buffer stride (u16)
  const int tid = threadIdx.x;
  const int lane = tid & 63;
  const int wv = tid >> 6, wm = wv >> 1, wn = wv & 1;
  const int quad = lane >> 4, r16 = lane & 15;

  const u16 *ga0, *gb0;
  {
    const int r0 = tid >> 2, sl0 = tid & 3;
    const int c0 = (sl0 ^ ((r0 >> 1) & 3)) * 8;
    ga0 = A + (size_t)(m0 + r0) * KA + k0 + c0;
    gb0 = Wc + (size_t)(n0 + r0) * KA + k0 + c0;
  }
  const int lofA0 = wv * 512;
  const int lofB0 = 4096 + wv * 512;

  auto STAGE = [&](int dstoff) {
    u16* dst_ = smem + dstoff;
    glds(ga0, dst_ + lofA0);
    glds(gb0, dst_ + lofB0);
    ga0 += 32; gb0 += 32;
  };

  v4f acc[2][4];
#pragma unroll
  for (int i = 0; i < 2; ++i)
#pragma unroll
    for (int j = 0; j < 4; ++j) { v4f z = {0.f, 0.f, 0.f, 0.f}; acc[i][j] = z; }

  auto COMPUTE = [&](int cbuf) {
    const u16* As_ = smem + cbuf * SB;
    const u16* Bs_ = As_ + 4096;
    v8s af[2], bf[4];
#pragma unroll
    for (int i = 0; i < 2; ++i) {
      const int ra = wm * 32 + i * 16 + r16;
      af[i] = *(const v8s*)&As_[ra * 32 + ((quad ^ ((ra >> 1) & 3)) * 8)];
    }
#pragma unroll
    for (int j = 0; j < 4; ++j) {
      const int rb = wn * 64 + j * 16 + r16;
      bf[j] = *(const v8s*)&Bs_[rb * 32 + ((quad ^ ((rb >> 1) & 3)) * 8)];
    }
#pragma unroll
    for (int i = 0; i < 2; ++i)
#pragma unroll
      for (int j = 0; j < 4; ++j)
        acc[i][j] = __builtin_amdgcn_mfma_f32_16x16x32_bf16(af[i], bf[j], acc[i][j], 0, 0, 0);
  };

  STAGE(0);
  STAGE(SB);
  int cb = 0, nb = 2;
  for (int t = 0; t < 9; ++t) {                   // steps 0..8; stages 2..10
    STAGE(nb * SB);
    asm volatile("s_waitcnt vmcnt(4)" ::: "memory");
    __builtin_amdgcn_s_barrier();
    COMPUTE(cb);
    asm volatile("s_waitcnt lgkmcnt(0)" ::: "memory");
    __builtin_amdgcn_s_barrier();
    cb = (cb == 2) ? 0 : cb + 1;
    nb = (nb == 2) ? 0 : nb + 1;
  }
  {                                               // steps 9, 10
    const int cb1 = (cb == 2) ? 0 : cb + 1;
    asm volatile("s_waitcnt vmcnt(2)" ::: "memory");
    __builtin_amdgcn_s_barrier();
    COMPUTE(cb);
    asm volatile("s_waitcnt vmcnt(0) lgkmcnt(0)" ::: "memory");
    __builtin_amdgcn_s_barrier();
    COMPUTE(cb1);
  }

  // store fragments: wave-contiguous f32 (1KB per (mtt,ntt) per wave), L2-kept
#pragma unroll
  for (int mtt = 0; mtt < 2; ++mtt)
#pragma unroll
    for (int ntt = 0; ntt < 4; ++ntt)
      *(v4f*)(pb + ((size_t)((wv * 2 + mtt) * 4 + ntt)) * 256 + lane * 4) = acc[mtt][ntt];
}

__global__ __launch_bounds__(512, 4) void gemm1_kernel(
    const u16* __restrict__ A, const u16* __restrict__ Wc,
    const float* __restrict__ rel_b, const float* __restrict__ tem_b,
    const float* __restrict__ bn_w, const float* __restrict__ bn_b,
    const float* __restrict__ bn_rm, const float* __restrict__ bn_rv,
    float* __restrict__ out, u16* __restrict__ BT,
    float* __restrict__ partial, const int splitk) {
  __shared__ u16 smem[36864];                     // 72KB (G=2: 3 x 24KB)
  const int id = blockIdx.x;
  if (id < 512) {                                 // 64 m-panels x 8 n, XCD-chunked
    const int wgid = (id & 7) * 64 + (id >> 3);   // 512 % 8 == 0 -> bijective
    gemm1_body<2>(A, Wc, rel_b, tem_b, bn_w, bn_b, bn_rm, bn_rv, out, BT, smem,
                  (wgid >> 3) * 256, (wgid & 7) * 128);
  } else if (splitk) {                            // 65th panel: 16 tiles x 6 K-splits
    const int sid = id - 512;
    const int tile = sid & 15, split = sid >> 4;
    gemm1_partial(A, Wc, partial + ((size_t)(split * 16 + tile)) * 16384, smem,
                  16384 + (tile >> 3) * 128, (tile & 7) * 128, split * 352);
  } else {                                        // fallback: full-K half tiles (R9)
    const int sid = id - 512;
    gemm1_body<1>(A, Wc, rel_b, tem_b, bn_w, bn_b, bn_rm, bn_rv, out, BT, smem,
                  16384 + (sid >> 3) * 128, (sid & 7) * 128);
  }
}

// ---------- tail_finish: reduce 6 K-split partials per tile + G=1 epilogue ----------
__global__ __launch_bounds__(512) void tail_finish_kernel(
    const float* __restrict__ partial,
    const float* __restrict__ rel_b, const float* __restrict__ tem_b,
    const float* __restrict__ bn_w, const float* __restrict__ bn_b,
    const float* __restrict__ bn_rm, const float* __restrict__ bn_rv,
    float* __restrict__ out, u16* __restrict__ BT) {
  __shared__ u16 smem[64 * 136];                  // 17408 B transpose buffer
  const int s = blockIdx.x;                       // 0..15
  const int m0 = 16384 + (s >> 3) * 128, n0 = (s & 7) * 128;
  const int tid = threadIdx.x;
  const int lane = tid & 63;
  const int wv = tid >> 6, wm = wv >> 1, wn = wv & 1;
  const int quad = lane >> 4, r16 = lane & 15;

  v4f acc[2][4];
  const float* pb = partial + (size_t)s * 16384;
#pragma unroll
  for (int mtt = 0; mtt < 2; ++mtt)
#pragma unroll
    for (int ntt = 0; ntt < 4; ++ntt) {
      const size_t fo = ((size_t)((wv * 2 + mtt) * 4 + ntt)) * 256 + lane * 4;
      v4f a = *(const v4f*)(pb + fo);
#pragma unroll
      for (int k = 1; k < 6; ++k) a += *(const v4f*)(pb + (size_t)k * 262144 + fo);
      acc[mtt][ntt] = a;
    }

  if (n0 < GG) {        // rel half
#pragma unroll
    for (int mtt = 0; mtt < 2; ++mtt) {
      const int mb = m0 + wm * 32 + mtt * 16 + quad * 4;
      const int bb = mb / FO;
      const int fo0 = mb - bb * FO;
      float inv[4], rm[4], bofs[4];
#pragma unroll
      for (int r = 0; r < 4; ++r) {
        const int fo = fo0 + r;
        inv[r] = bn_w[fo] * rsqrtf(bn_rv[fo] + 1e-5f);
        rm[r] = bn_rm[fo]; bofs[r] = bn_b[fo];
      }
#pragma unroll
      for (int ntt = 0; ntt < 4; ++ntt) {
        const int n = n0 + wn * 64 + ntt * 16 + r16;
        const float rbn = rel_b[n];
#pragma unroll
        for (int r = 0; r < 4; ++r) {
          float val = (fast_tanh(acc[mtt][ntt][r] + rbn) - rm[r]) * inv[r] + bofs[r];
          __builtin_nontemporal_store(val, out + (size_t)(mb + r) * N1 + n);
        }
      }
    }
  } else {              // tem half: LDS transpose -> BT (same as gemm1_body<1>)
#pragma unroll
    for (int p = 0; p < 2; ++p) {
      if (p) __syncthreads();
      if (wn == p) {
#pragma unroll
        for (int mtt = 0; mtt < 2; ++mtt) {
          const int il = wm * 32 + mtt * 16 + quad * 4;
#pragma unroll
          for (int ntt = 0; ntt < 4; ++ntt) {
            const int gl = ntt * 16 + r16;
            const float tb = tem_b[(n0 - GG) + p * 64 + gl];
            ushort4 w;
            w.x = f2bf(acc[mtt][ntt][0] + tb);
            w.y = f2bf(acc[mtt][ntt][1] + tb);
            w.z = f2bf(acc[mtt][ntt][2] + tb);
            w.w = f2bf(acc[mtt][ntt][3] + tb);
            *(ushort4*)&smem[gl * 136 + il] = w;
          }
        }
      }
      __syncthreads();
#pragma unroll
      for (int pass = 0; pass < 2; ++pass) {
        const int gl = pass * 32 + (tid >> 4);
        const int ch = tid & 15;
        const int m = m0 + ch * 8;
        const int b1 = m / FO;
        const int i1 = m - b1 * FO;
        v8s val = *(const v8s*)&smem[gl * 136 + ch * 8];
        const int g = (n0 - GG) + p * 64 + gl;
        *(v8s*)(BT + ((size_t)(b1 * GG + g)) * K2P + i1) = val;
      }
    }
  }
}

// ---------- GEMM2: batched [640x576]x[576x512], 128x256 tiles ----------
#define G2_STAGE(DST)                                                                            \
  do {                                                                                           \
    u16* dst_ = smem + (DST);                                                                    \
    glds(ga0, dst_ + lofA0); glds(gb0, dst_ + lofB0); glds(gb1, dst_ + lofB1);                   \
    ga0 += 32; gb0 += 32; gb1 += 32;                                                             \
  } while (0)

#define G2_COMPUTE(CB)                                                                           \
  do {                                                                                           \
    const u16* As_ = smem + (CB) * 12288;                                                        \
    const u16* Bs_ = As_ + 4096;                                                                 \
    v8s af[4], bf[4];                                                                            \
    _Pragma("unroll") for (int t4 = 0; t4 < 4; ++t4) {                                           \
      const int ra = wm * 64 + t4 * 16 + r16;                                                    \
      const int rb = wn * 64 + t4 * 16 + r16;                                                    \
      af[t4] = *(const v8s*)&As_[ra * 32 + ((quad ^ ((ra >> 1) & 3)) * 8)];                      \
      bf[t4] = *(const v8s*)&Bs_[rb * 32 + ((quad ^ ((rb >> 1) & 3)) * 8)];                      \
    }                                                                                            \
    _Pragma("unroll") for (int mtt = 0; mtt < 4; ++mtt)                                          \
      _Pragma("unroll") for (int ntt = 0; ntt < 4; ++ntt)                                        \
        acc[mtt][ntt] =                                                                          \
            __builtin_amdgcn_mfma_f32_16x16x32_bf16(af[mtt], bf[ntt], acc[mtt][ntt], 0, 0, 0);   \
  } while (0)

__global__ __launch_bounds__(512, 4) void gemm2_kernel(
    const u16* __restrict__ A2, const u16* __restrict__ BT,
    const float* __restrict__ tsum,
    const float* __restrict__ bn_w, const float* __restrict__ bn_b,
    const float* __restrict__ bn_rm, const float* __restrict__ bn_rv,
    float* __restrict__ out) {
  __shared__ u16 smem[36864];                     // 72KB: 3 bufs x (A 8KB | B 16KB)
  const int tid = threadIdx.x;
  const int lane = tid & 63;
  const int wv = tid >> 6, wm = wv >> 2, wn = wv & 3;   // 2m x 4n waves of 64x64
  const int m0 = blockIdx.x * 128;                // 5 tiles over 640
  const int n0 = blockIdx.y * 256;                // 2 tiles over 512
  const int b = blockIdx.z;
  const u16* Ab = A2 + (size_t)b * M2 * K2P;
  const u16* Bb = BT + (size_t)b * GG * K2P;
  const int quad = lane >> 4, r16 = lane & 15;

  const u16 *ga0, *gb0, *gb1;
  {
    const int r0 = tid >> 2, sl0 = tid & 3;
    const int c0 = (sl0 ^ ((r0 >> 1) & 3)) * 8;
    ga0 = Ab + (size_t)(m0 + r0) * K2P + c0;
    gb0 = Bb + (size_t)(n0 + r0) * K2P + c0;
    gb1 = Bb + (size_t)(n0 + 128 + r0) * K2P + c0;
  }
  const int lofA0 = wv * 512;
  const int lofB0 = 4096 + wv * 512;
  const int lofB1 = 8192 + wv * 512;

  v4f acc[4][4];
#pragma unroll
  for (int i = 0; i < 4; ++i)
#pragma unroll
    for (int j = 0; j < 4; ++j) { v4f z = {0.f, 0.f, 0.f, 0.f}; acc[i][j] = z; }

  G2_STAGE(0);
  G2_STAGE(12288);

  int cb = 0, nb = 2;
  for (int t = 0; t < 16; ++t) {
    G2_STAGE(nb * 12288);
    asm volatile("s_waitcnt vmcnt(6)" ::: "memory");
    __builtin_amdgcn_s_barrier();
    G2_COMPUTE(cb);
    asm volatile("s_waitcnt lgkmcnt(0)" ::: "memory");
    __builtin_amdgcn_s_barrier();
    cb = (cb == 2) ? 0 : cb + 1;
    nb = (nb == 2) ? 0 : nb + 1;
  }
  {
    const int cb1 = (cb == 2) ? 0 : cb + 1;
    asm volatile("s_waitcnt vmcnt(3)" ::: "memory");
    __builtin_amdgcn_s_barrier();
    G2_COMPUTE(cb);
    asm volatile("s_waitcnt vmcnt(0) lgkmcnt(0)" ::: "memory");
    __builtin_amdgcn_s_barrier();
    G2_COMPUTE(cb1);
  }

#pragma unroll
  for (int mtt = 0; mtt < 4; ++mtt) {
    const int ibase = m0 + wm * 64 + mtt * 16 + quad * 4;
    if (ibase >= FO) continue;
    float ts[4], inv[4], rm[4], bofs[4];
#pragma unroll
    for (int r = 0; r < 4; ++r) {
      const int i = ibase + r;
      ts[r] = 1.f / tsum[(size_t)b * FO + i];
      inv[r] = bn_w[i] * rsqrtf(bn_rv[i] + 1e-5f);
      rm[r] = bn_rm[i]; bofs[r] = bn_b[i];
    }
#pragma unroll
    for (int ntt = 0; ntt < 4; ++ntt) {
      const int g = n0 + wn * 64 + ntt * 16 + r16;
#pragma unroll
      for (int r = 0; r < 4; ++r) {
        float val = (fast_tanh(acc[mtt][ntt][r] * ts[r]) - rm[r]) * inv[r] + bofs[r];
        __builtin_nontemporal_store(val, out + ((size_t)(b * FO + (ibase + r))) * N1 + GG + g);
      }
    }
  }
}

extern "C" void kernel_launch(void* const* d_in, const int* in_sizes, int n_in,
                              void* d_out, int out_size, void* d_ws, size_t ws_size,
                              hipStream_t stream) {
  const float* region_feats = (const float*)d_in[0];
  // d_in[1] region_masks: unused by reference
  const int* rel_feats = (const int*)d_in[2];
  const float* tem_feats = (const float*)d_in[3];
  const float* rel_W = (const float*)d_in[4];
  const float* rel_b = (const float*)d_in[5];
  const float* rel_emb = (const float*)d_in[6];
  const float* tem_W = (const float*)d_in[7];
  const float* tem_b = (const float*)d_in[8];
  const float* bn_w = (const float*)d_in[9];
  const float* bn_b = (const float*)d_in[10];
  const float* bn_rm = (const float*)d_in[11];
  const float* bn_rv = (const float*)d_in[12];
  float* out = (float*)d_out;

  // Workspace layout
  char* base = (char*)d_ws;
  u16* A1 = (u16*)base;                                   // [16640][2112] bf16 : 70,287,360
  u16* Wc = (u16*)(base + 70287360);                      // [1024][2112] bf16  :  4,325,376
  u16* A2 = (u16*)(base + 74612736);                      // [32][640][576] bf16: 23,592,960
  u16* BT = (u16*)(base + 98205696);                      // [32][512][576] bf16: 18,874,368
  float* tsum = (float*)(base + 117080064);               // [32*520] f32       :     66,560
  float* partial = (float*)(base + 117146624);            // [6][16][16384] f32 :  6,291,456
  const int splitk = (ws_size >= 123438080u) ? 1 : 0;     // fallback to R9 grid if ws too small

  prep_all_kernel<<<PREP_ROWS + 2560, 512, 0, stream>>>(
      region_feats, rel_feats, rel_W, tem_W, rel_emb, tem_feats, A1, Wc, A2, tsum);
  gemm1_kernel<<<splitk ? 608 : 528, 512, 0, stream>>>(A1, Wc, rel_b, tem_b,
                                                       bn_w, bn_b, bn_rm, bn_rv, out, BT,
                                                       partial, splitk);
  if (splitk)
    tail_finish_kernel<<<16, 512, 0, stream>>>(partial, rel_b, tem_b,
                                               bn_w, bn_b, bn_rm, bn_rv, out, BT);
  gemm2_kernel<<<dim3(5, 2, 32), 512, 0, stream>>>(A2, BT, tsum,
                                                   bn_w, bn_b, bn_rm, bn_rv, out);
}